// Round 1
// baseline (1794.276 us; speedup 1.0000x reference)
//
#include <hip/hip_runtime.h>
#include <hip/hip_bf16.h>

#define TT 12
#define NNODE 10000
#define NEDGE 160000
#define NPAIR 30000
#define DINq 128
#define HH 64
#define NG 24  // 2*T

// ---------------- Kernel 1: xn = x @ w_neigh  (rows = NG*NNODE) ----------------
__global__ __launch_bounds__(256) void k_xn(const float* __restrict__ x,
                                            const float* __restrict__ w_neigh,
                                            float* __restrict__ xn) {
    __shared__ float lw[DINq * HH];  // 32 KB
    for (int i = threadIdx.x; i < DINq * HH; i += 256) lw[i] = w_neigh[i];
    __syncthreads();
    const int lane = threadIdx.x & 63;
    const int wave = threadIdx.x >> 6;
    const int nrows = NG * NNODE;  // 240000 (even)
    // 2 rows per wave, 8 per block
    for (int base = blockIdx.x * 8 + wave * 2; base < nrows; base += gridDim.x * 8) {
        const float* xr0 = x + (size_t)base * DINq;
        const float* xr1 = xr0 + DINq;
        float acc0 = 0.f, acc1 = 0.f;
        #pragma unroll
        for (int k = 0; k < DINq; k += 4) {
            float4 a = *(const float4*)(xr0 + k);
            float4 b = *(const float4*)(xr1 + k);
            float w0 = lw[(k + 0) * HH + lane];
            float w1 = lw[(k + 1) * HH + lane];
            float w2 = lw[(k + 2) * HH + lane];
            float w3 = lw[(k + 3) * HH + lane];
            acc0 += a.x * w0; acc1 += b.x * w0;
            acc0 += a.y * w1; acc1 += b.y * w1;
            acc0 += a.z * w2; acc1 += b.z * w2;
            acc0 += a.w * w3; acc1 += b.w * w3;
        }
        xn[(size_t)base * HH + lane] = acc0;
        xn[(size_t)(base + 1) * HH + lane] = acc1;
    }
}

// ---------------- Kernel 2: scatter-aggregate msum += xn[src], deg += 1 ----------------
__global__ __launch_bounds__(256) void k_agg(const int* __restrict__ src,
                                             const int* __restrict__ dst,
                                             const float* __restrict__ xn,
                                             float* __restrict__ msum,
                                             float* __restrict__ deg) {
    const int g = blockIdx.y;
    const int lane = threadIdx.x & 63;
    const int wv = blockIdx.x * 4 + (threadIdx.x >> 6);
    const int nw = gridDim.x * 4;
    const int* sg = src + (size_t)g * NEDGE;
    const int* dgp = dst + (size_t)g * NEDGE;
    const float* xg = xn + (size_t)g * NNODE * HH;
    float* mg = msum + (size_t)g * NNODE * HH;
    float* degg = deg + g * NNODE;
    // 4-edge unroll: issue 4 gathers before 4 atomics (latency hiding)
    for (int e0 = wv * 4; e0 < NEDGE; e0 += nw * 4) {  // NEDGE % 4 == 0
        int s[4], d[4];
        float v[4];
        #pragma unroll
        for (int i = 0; i < 4; ++i) { s[i] = sg[e0 + i]; d[i] = dgp[e0 + i]; }
        #pragma unroll
        for (int i = 0; i < 4; ++i) v[i] = xg[(size_t)s[i] * HH + lane];
        #pragma unroll
        for (int i = 0; i < 4; ++i) atomicAdd(&mg[(size_t)d[i] * HH + lane], v[i]);
        if (lane == 0) {
            #pragma unroll
            for (int i = 0; i < 4; ++i) atomicAdd(&degg[d[i]], 1.0f);
        }
    }
}

// ---------------- Kernel 3: h = L2norm(x @ w_self + b_sage + msum/deg) ----------------
__global__ __launch_bounds__(256) void k_fin(const float* __restrict__ x,
                                             const float* __restrict__ w_self,
                                             const float* __restrict__ b_sage,
                                             const float* __restrict__ msum,
                                             const float* __restrict__ deg,
                                             float* __restrict__ h) {
    __shared__ float lw[DINq * HH];
    for (int i = threadIdx.x; i < DINq * HH; i += 256) lw[i] = w_self[i];
    __syncthreads();
    const int lane = threadIdx.x & 63;
    const int wave = threadIdx.x >> 6;
    const int nrows = NG * NNODE;
    for (int base = blockIdx.x * 8 + wave * 2; base < nrows; base += gridDim.x * 8) {
        const float* xr0 = x + (size_t)base * DINq;
        const float* xr1 = xr0 + DINq;
        float acc0 = b_sage[lane], acc1 = acc0;
        #pragma unroll
        for (int k = 0; k < DINq; k += 4) {
            float4 a = *(const float4*)(xr0 + k);
            float4 b = *(const float4*)(xr1 + k);
            float w0 = lw[(k + 0) * HH + lane];
            float w1 = lw[(k + 1) * HH + lane];
            float w2 = lw[(k + 2) * HH + lane];
            float w3 = lw[(k + 3) * HH + lane];
            acc0 += a.x * w0; acc1 += b.x * w0;
            acc0 += a.y * w1; acc1 += b.y * w1;
            acc0 += a.z * w2; acc1 += b.z * w2;
            acc0 += a.w * w3; acc1 += b.w * w3;
        }
        #pragma unroll
        for (int r = 0; r < 2; ++r) {
            int row = base + r;
            float acc = r == 0 ? acc0 : acc1;
            float dgv = deg[row];
            dgv = dgv > 1.f ? dgv : 1.f;
            acc += msum[(size_t)row * HH + lane] / dgv;
            float sq = acc * acc;
            #pragma unroll
            for (int off = 32; off; off >>= 1) sq += __shfl_xor(sq, off);
            float nrm = sqrtf(sq);
            nrm = nrm > 1e-12f ? nrm : 1e-12f;
            h[(size_t)row * HH + lane] = acc / nrm;
        }
    }
}

__device__ __forceinline__ float sigmoidf_(float v) {
    return 1.0f / (1.0f + __expf(-v));
}

// ---------------- Kernel 4: pair / temporal attention ----------------
__global__ __launch_bounds__(256) void k_pair(const float* __restrict__ h,   // [NG][N][H]
                                              const int* __restrict__ idx,   // [2][T][P]
                                              const float* __restrict__ w_ff2,  // [128]
                                              const float* __restrict__ b_ff2p,
                                              const float* __restrict__ w_ff1,  // [12]
                                              const float* __restrict__ b_ff1p,
                                              const float* __restrict__ w_out,  // [128]
                                              float* __restrict__ out) {        // [T][P]
    const int lane = threadIdx.x & 63;
    const int wave = threadIdx.x >> 6;
    const int p = blockIdx.x * 4 + wave;
    if (p >= NPAIR) return;
    const float wf2_0 = w_ff2[lane], wf2_1 = w_ff2[lane + 64];
    const float wo_0 = w_out[lane], wo_1 = w_out[lane + 64];
    const float bf2 = *b_ff2p, bf1 = *b_ff1p;

    float tv0[TT], tv1[TT], q[TT];
    #pragma unroll
    for (int t = 0; t < TT; ++t) {
        int i0 = idx[t * NPAIR + p];
        int i1 = idx[(TT + t) * NPAIR + p];
        tv0[t] = h[((size_t)t * NNODE + i0) * HH + lane];
        tv1[t] = h[((size_t)(TT + t) * NNODE + i1) * HH + lane];
        float part = tv0[t] * wf2_0 + tv1[t] * wf2_1;
        #pragma unroll
        for (int off = 32; off; off >>= 1) part += __shfl_xor(part, off);
        q[t] = part;
    }

    // window scores (scalar per pair, computed redundantly per lane)
    float s[3];
    #pragma unroll
    for (int k = 1; k <= 3; ++k) {
        float acc = bf1;
        #pragma unroll
        for (int t = 0; t < TT; ++t) {
            float dq = q[t] - (t >= k ? q[t - k] : 0.f);
            float r = dq + bf2;
            r = r > 0.f ? r : 0.f;
            acc += r * w_ff1[t];
        }
        s[k - 1] = acc;
    }
    float m = fmaxf(s[0], fmaxf(s[1], s[2]));
    float e0 = __expf(s[0] - m), e1 = __expf(s[1] - m), e2 = __expf(s[2] - m);
    float inv = 1.f / (e0 + e1 + e2);
    float sw0 = e0 * inv, sw1 = e1 * inv, sw2 = e2 * inv;

    #pragma unroll
    for (int t = 0; t < TT; ++t) {
        float a0, a1;
        {
            float d0 = tv0[t] - (t >= 1 ? tv0[t - 1] : 0.f);
            float d1 = tv1[t] - (t >= 1 ? tv1[t - 1] : 0.f);
            a0 = sw0 * sigmoidf_(d0);
            a1 = sw0 * sigmoidf_(d1);
        }
        {
            float d0 = tv0[t] - (t >= 2 ? tv0[t - 2] : 0.f);
            float d1 = tv1[t] - (t >= 2 ? tv1[t - 2] : 0.f);
            a0 += sw1 * sigmoidf_(d0);
            a1 += sw1 * sigmoidf_(d1);
        }
        {
            float d0 = tv0[t] - (t >= 3 ? tv0[t - 3] : 0.f);
            float d1 = tv1[t] - (t >= 3 ? tv1[t - 3] : 0.f);
            a0 += sw2 * sigmoidf_(d0);
            a1 += sw2 * sigmoidf_(d1);
        }
        float o = tv0[t] * a0 * wo_0 + tv1[t] * a1 * wo_1;
        #pragma unroll
        for (int off = 32; off; off >>= 1) o += __shfl_xor(o, off);
        if (lane == 0) out[t * NPAIR + p] = o;
    }
}

extern "C" void kernel_launch(void* const* d_in, const int* in_sizes, int n_in,
                              void* d_out, int out_size, void* d_ws, size_t ws_size,
                              hipStream_t stream) {
    const float* x      = (const float*)d_in[0];
    const int*   src    = (const int*)d_in[1];
    const int*   dst    = (const int*)d_in[2];
    const int*   idx    = (const int*)d_in[3];
    const float* w_self = (const float*)d_in[4];
    const float* w_neigh= (const float*)d_in[5];
    const float* b_sage = (const float*)d_in[6];
    const float* w_ff2  = (const float*)d_in[7];
    const float* b_ff2  = (const float*)d_in[8];
    const float* w_ff1  = (const float*)d_in[9];
    const float* b_ff1  = (const float*)d_in[10];
    const float* w_out  = (const float*)d_in[11];
    float* out = (float*)d_out;

    char* ws = (char*)d_ws;
    const size_t HB = (size_t)NG * NNODE * HH * sizeof(float);  // 61,440,000 B
    float* xn_h = (float*)ws;                 // xn, later overwritten by h
    float* msum = (float*)(ws + HB);
    float* deg  = (float*)(ws + 2 * HB);      // NG*NNODE floats

    // zero msum + deg (contiguous)
    hipMemsetAsync(ws + HB, 0, HB + (size_t)NG * NNODE * sizeof(float), stream);

    k_xn<<<2048, 256, 0, stream>>>(x, w_neigh, xn_h);
    dim3 gagg(160, NG);
    k_agg<<<gagg, 256, 0, stream>>>(src, dst, xn_h, msum, deg);
    k_fin<<<2048, 256, 0, stream>>>(x, w_self, b_sage, msum, deg, xn_h);
    k_pair<<<NPAIR / 4, 256, 0, stream>>>(xn_h, idx, w_ff2, b_ff2, w_ff1, b_ff1,
                                          w_out, out);
}

// Round 2
// 1275.281 us; speedup vs baseline: 1.4070x; 1.4070x over previous
//
#include <hip/hip_runtime.h>
#include <hip/hip_bf16.h>

#define TT 12
#define NNODE 10000
#define NEDGE 160000
#define NPAIR 30000
#define DINq 128
#define HH 64
#define NG 24            // 2*T
#define NROWS (NG * NNODE)
#define NEDGES_ALL (NG * NEDGE)

// ---------------- Kernel 1: xn = x @ w_neigh  (8 rows per wave) ----------------
__global__ __launch_bounds__(256) void k_xn(const float* __restrict__ x,
                                            const float* __restrict__ w_neigh,
                                            float* __restrict__ xn) {
    __shared__ float lw[DINq * HH];  // 32 KB
    for (int i = threadIdx.x; i < DINq * HH; i += 256) lw[i] = w_neigh[i];
    __syncthreads();
    const int lane = threadIdx.x & 63;
    const int wave = threadIdx.x >> 6;
    const int base = blockIdx.x * 32 + wave * 8;  // 7500 blocks * 32 rows = 240000
    const float* xr = x + (size_t)base * DINq;
    float acc[8];
    #pragma unroll
    for (int r = 0; r < 8; ++r) acc[r] = 0.f;
    for (int k = 0; k < DINq; k += 4) {
        float w0 = lw[(k + 0) * HH + lane];
        float w1 = lw[(k + 1) * HH + lane];
        float w2 = lw[(k + 2) * HH + lane];
        float w3 = lw[(k + 3) * HH + lane];
        #pragma unroll
        for (int r = 0; r < 8; ++r) {
            float4 a = *(const float4*)(xr + (size_t)r * DINq + k);
            acc[r] += a.x * w0 + a.y * w1 + a.z * w2 + a.w * w3;
        }
    }
    #pragma unroll
    for (int r = 0; r < 8; ++r)
        xn[(size_t)(base + r) * HH + lane] = acc[r];
}

// ---------------- Kernel 2a: degree histogram ----------------
__global__ __launch_bounds__(256) void k_hist(const int* __restrict__ dst,
                                              int* __restrict__ deg_i) {
    int e = blockIdx.x * 256 + threadIdx.x;
    if (e >= NEDGES_ALL) return;
    int g = e / NEDGE;
    atomicAdd(&deg_i[g * NNODE + dst[e]], 1);
}

// ---------------- Kernel 2b: per-graph exclusive prefix sum -> cursor ----------------
__global__ __launch_bounds__(256) void k_scan(const int* __restrict__ deg_i,
                                              int* __restrict__ cursor) {
    const int g = blockIdx.x;
    __shared__ int sbuf[256];
    __shared__ int srun;
    if (threadIdx.x == 0) srun = 0;
    __syncthreads();
    for (int c0 = 0; c0 < NNODE; c0 += 256) {
        int n = c0 + threadIdx.x;
        int v = (n < NNODE) ? deg_i[g * NNODE + n] : 0;
        sbuf[threadIdx.x] = v;
        __syncthreads();
        #pragma unroll
        for (int d = 1; d < 256; d <<= 1) {
            int t = (threadIdx.x >= d) ? sbuf[threadIdx.x - d] : 0;
            __syncthreads();
            sbuf[threadIdx.x] += t;
            __syncthreads();
        }
        int incl = sbuf[threadIdx.x];
        int run = srun;
        if (n < NNODE) cursor[g * NNODE + n] = run + incl - v;  // exclusive
        __syncthreads();
        if (threadIdx.x == 255) srun = run + incl;
        __syncthreads();
    }
}

// ---------------- Kernel 2c: fill CSR (src ids grouped by dst) ----------------
__global__ __launch_bounds__(256) void k_fill(const int* __restrict__ src,
                                              const int* __restrict__ dst,
                                              int* __restrict__ cursor,
                                              int* __restrict__ csr) {
    int e = blockIdx.x * 256 + threadIdx.x;
    if (e >= NEDGES_ALL) return;
    int g = e / NEDGE;
    int pos = atomicAdd(&cursor[g * NNODE + dst[e]], 1);
    csr[(size_t)g * NEDGE + pos] = src[e];
}

// ---------------- Kernel 2d: gather-mean per node (no f32 atomics) ----------------
__global__ __launch_bounds__(256) void k_gath(const int* __restrict__ csr,
                                              const int* __restrict__ cursor,
                                              const int* __restrict__ deg_i,
                                              const float* __restrict__ xn,
                                              float* __restrict__ msum) {
    const int lane = threadIdx.x & 63;
    const int row = blockIdx.x * 4 + (threadIdx.x >> 6);
    if (row >= NROWS) return;
    const int g = row / NNODE;
    const int end = cursor[row];        // after k_fill, cursor[row] == off + deg
    const int dg = deg_i[row];
    const int start = end - dg;
    const float* xg = xn + (size_t)g * NNODE * HH;
    const int* cs = csr + (size_t)g * NEDGE;
    float acc = 0.f;
    int j = start;
    for (; j + 4 <= end; j += 4) {
        int s0 = cs[j], s1 = cs[j + 1], s2 = cs[j + 2], s3 = cs[j + 3];
        float v0 = xg[(size_t)s0 * HH + lane];
        float v1 = xg[(size_t)s1 * HH + lane];
        float v2 = xg[(size_t)s2 * HH + lane];
        float v3 = xg[(size_t)s3 * HH + lane];
        acc += v0 + v1 + v2 + v3;
    }
    for (; j < end; ++j) acc += xg[(size_t)cs[j] * HH + lane];
    float mean = (dg > 0) ? acc / (float)dg : 0.f;
    msum[(size_t)row * HH + lane] = mean;
}

// ---------------- Kernel 3: h = L2norm(x @ w_self + b_sage + mean) ----------------
__global__ __launch_bounds__(256) void k_fin(const float* __restrict__ x,
                                             const float* __restrict__ w_self,
                                             const float* __restrict__ b_sage,
                                             const float* __restrict__ msum,
                                             float* __restrict__ h) {
    __shared__ float lw[DINq * HH];
    for (int i = threadIdx.x; i < DINq * HH; i += 256) lw[i] = w_self[i];
    __syncthreads();
    const int lane = threadIdx.x & 63;
    const int wave = threadIdx.x >> 6;
    const int base = blockIdx.x * 32 + wave * 8;
    const float* xr = x + (size_t)base * DINq;
    float acc[8];
    float bsv = b_sage[lane];
    #pragma unroll
    for (int r = 0; r < 8; ++r) acc[r] = bsv;
    for (int k = 0; k < DINq; k += 4) {
        float w0 = lw[(k + 0) * HH + lane];
        float w1 = lw[(k + 1) * HH + lane];
        float w2 = lw[(k + 2) * HH + lane];
        float w3 = lw[(k + 3) * HH + lane];
        #pragma unroll
        for (int r = 0; r < 8; ++r) {
            float4 a = *(const float4*)(xr + (size_t)r * DINq + k);
            acc[r] += a.x * w0 + a.y * w1 + a.z * w2 + a.w * w3;
        }
    }
    #pragma unroll
    for (int r = 0; r < 8; ++r) {
        int row = base + r;
        float v = acc[r] + msum[(size_t)row * HH + lane];
        float sq = v * v;
        #pragma unroll
        for (int off = 32; off; off >>= 1) sq += __shfl_xor(sq, off);
        float nrm = sqrtf(sq);
        nrm = nrm > 1e-12f ? nrm : 1e-12f;
        h[(size_t)row * HH + lane] = v / nrm;
    }
}

__device__ __forceinline__ float sigmoidf_(float v) {
    return 1.0f / (1.0f + __expf(-v));
}

// ---------------- Kernel 4: pair / temporal attention ----------------
__global__ __launch_bounds__(256) void k_pair(const float* __restrict__ h,   // [NG][N][H]
                                              const int* __restrict__ idx,   // [2][T][P]
                                              const float* __restrict__ w_ff2,  // [128]
                                              const float* __restrict__ b_ff2p,
                                              const float* __restrict__ w_ff1,  // [12]
                                              const float* __restrict__ b_ff1p,
                                              const float* __restrict__ w_out,  // [128]
                                              float* __restrict__ out) {        // [T][P]
    const int lane = threadIdx.x & 63;
    const int wave = threadIdx.x >> 6;
    const int p = blockIdx.x * 4 + wave;
    if (p >= NPAIR) return;
    const float wf2_0 = w_ff2[lane], wf2_1 = w_ff2[lane + 64];
    const float wo_0 = w_out[lane], wo_1 = w_out[lane + 64];
    const float bf2 = *b_ff2p, bf1 = *b_ff1p;

    float tv0[TT], tv1[TT], q[TT];
    #pragma unroll
    for (int t = 0; t < TT; ++t) {
        int i0 = idx[t * NPAIR + p];
        int i1 = idx[(TT + t) * NPAIR + p];
        tv0[t] = h[((size_t)t * NNODE + i0) * HH + lane];
        tv1[t] = h[((size_t)(TT + t) * NNODE + i1) * HH + lane];
        float part = tv0[t] * wf2_0 + tv1[t] * wf2_1;
        #pragma unroll
        for (int off = 32; off; off >>= 1) part += __shfl_xor(part, off);
        q[t] = part;
    }

    float s[3];
    #pragma unroll
    for (int k = 1; k <= 3; ++k) {
        float acc = bf1;
        #pragma unroll
        for (int t = 0; t < TT; ++t) {
            float dq = q[t] - (t >= k ? q[t - k] : 0.f);
            float r = dq + bf2;
            r = r > 0.f ? r : 0.f;
            acc += r * w_ff1[t];
        }
        s[k - 1] = acc;
    }
    float m = fmaxf(s[0], fmaxf(s[1], s[2]));
    float e0 = __expf(s[0] - m), e1 = __expf(s[1] - m), e2 = __expf(s[2] - m);
    float inv = 1.f / (e0 + e1 + e2);
    float sw0 = e0 * inv, sw1 = e1 * inv, sw2 = e2 * inv;

    #pragma unroll
    for (int t = 0; t < TT; ++t) {
        float a0, a1;
        {
            float d0 = tv0[t] - (t >= 1 ? tv0[t - 1] : 0.f);
            float d1 = tv1[t] - (t >= 1 ? tv1[t - 1] : 0.f);
            a0 = sw0 * sigmoidf_(d0);
            a1 = sw0 * sigmoidf_(d1);
        }
        {
            float d0 = tv0[t] - (t >= 2 ? tv0[t - 2] : 0.f);
            float d1 = tv1[t] - (t >= 2 ? tv1[t - 2] : 0.f);
            a0 += sw1 * sigmoidf_(d0);
            a1 += sw1 * sigmoidf_(d1);
        }
        {
            float d0 = tv0[t] - (t >= 3 ? tv0[t - 3] : 0.f);
            float d1 = tv1[t] - (t >= 3 ? tv1[t - 3] : 0.f);
            a0 += sw2 * sigmoidf_(d0);
            a1 += sw2 * sigmoidf_(d1);
        }
        float o = tv0[t] * a0 * wo_0 + tv1[t] * a1 * wo_1;
        #pragma unroll
        for (int off = 32; off; off >>= 1) o += __shfl_xor(o, off);
        if (lane == 0) out[t * NPAIR + p] = o;
    }
}

extern "C" void kernel_launch(void* const* d_in, const int* in_sizes, int n_in,
                              void* d_out, int out_size, void* d_ws, size_t ws_size,
                              hipStream_t stream) {
    const float* x      = (const float*)d_in[0];
    const int*   src    = (const int*)d_in[1];
    const int*   dst    = (const int*)d_in[2];
    const int*   idx    = (const int*)d_in[3];
    const float* w_self = (const float*)d_in[4];
    const float* w_neigh= (const float*)d_in[5];
    const float* b_sage = (const float*)d_in[6];
    const float* w_ff2  = (const float*)d_in[7];
    const float* b_ff2  = (const float*)d_in[8];
    const float* w_ff1  = (const float*)d_in[9];
    const float* b_ff1  = (const float*)d_in[10];
    const float* w_out  = (const float*)d_in[11];
    float* out = (float*)d_out;

    char* ws = (char*)d_ws;
    const size_t HB = (size_t)NROWS * HH * sizeof(float);       // 61,440,000 B
    const size_t NB = (size_t)NROWS * sizeof(int);              //    960,000 B
    float* xn_h  = (float*)ws;                                  // xn, later h
    float* msum  = (float*)(ws + HB);                           // mean (H-dim)
    int*   deg_i = (int*)(ws + 2 * HB);
    int*   cursor= (int*)(ws + 2 * HB + NB);
    int*   csr   = (int*)(ws + 2 * HB + 2 * NB);                // NG*NEDGE ints = 15.36 MB

    hipMemsetAsync(deg_i, 0, NB, stream);                       // only the histogram

    k_xn<<<NROWS / 32, 256, 0, stream>>>(x, w_neigh, xn_h);
    k_hist<<<NEDGES_ALL / 256, 256, 0, stream>>>(dst, deg_i);
    k_scan<<<NG, 256, 0, stream>>>(deg_i, cursor);
    k_fill<<<NEDGES_ALL / 256, 256, 0, stream>>>(src, dst, cursor, csr);
    k_gath<<<NROWS / 4, 256, 0, stream>>>(csr, cursor, deg_i, xn_h, msum);
    k_fin<<<NROWS / 32, 256, 0, stream>>>(x, w_self, b_sage, msum, xn_h);
    k_pair<<<NPAIR / 4, 256, 0, stream>>>(xn_h, idx, w_ff2, b_ff2, w_ff1, b_ff1,
                                          w_out, out);
}

// Round 4
// 874.013 us; speedup vs baseline: 2.0529x; 1.4591x over previous
//
#include <hip/hip_runtime.h>
#include <hip/hip_bf16.h>

#define TT 12
#define NNODE 10000
#define NEDGE 160000
#define NPAIR 30000
#define DIN 128
#define HH 64
#define NG 24            // 2*T
#define NROWS (NG * NNODE)
#define NEALL (NG * NEDGE)

typedef __attribute__((ext_vector_type(8))) short short8v;  // 8 bf16 (4 VGPRs)
typedef __attribute__((ext_vector_type(4))) float f32x4;

__device__ __forceinline__ short f2bf(float f) {  // RNE f32->bf16
    unsigned u = __float_as_uint(f);
    unsigned r = u + 0x7fffu + ((u >> 16) & 1u);
    return (short)(r >> 16);
}
__device__ __forceinline__ float bf2f(short s) {
    return __uint_as_float(((unsigned)(unsigned short)s) << 16);
}

// ---------------- GEMM 1: xn = x @ w_neigh (bf16x2 split MFMA) ----------------
__global__ __launch_bounds__(256) void k_gemm_n(const float* __restrict__ x,
                                                const float* __restrict__ w,   // [128][64]
                                                float* __restrict__ xn) {      // [NROWS][64]
    const int l = threadIdx.x & 63;
    const int wv = threadIdx.x >> 6;
    const int base = blockIdx.x * 64 + wv * 16;
    const int r15 = l & 15, q = l >> 4;
    f32x4 acc[4];
    #pragma unroll
    for (int c = 0; c < 4; ++c) acc[c] = (f32x4)0.f;
    #pragma unroll
    for (int s = 0; s < 4; ++s) {
        const float* xr = x + (size_t)(base + r15) * DIN + s * 32 + q * 8;
        float4 a0 = *(const float4*)xr;
        float4 a1 = *(const float4*)(xr + 4);
        float av[8] = {a0.x, a0.y, a0.z, a0.w, a1.x, a1.y, a1.z, a1.w};
        short8v ah, al;
        #pragma unroll
        for (int j = 0; j < 8; ++j) {
            short h = f2bf(av[j]); ah[j] = h; al[j] = f2bf(av[j] - bf2f(h));
        }
        #pragma unroll
        for (int c = 0; c < 4; ++c) {
            const float* wp = w + (size_t)(s * 32 + q * 8) * HH + c * 16 + r15;
            short8v bh, bl;
            #pragma unroll
            for (int j = 0; j < 8; ++j) {
                float v = wp[(size_t)j * HH];
                short h = f2bf(v); bh[j] = h; bl[j] = f2bf(v - bf2f(h));
            }
            acc[c] = __builtin_amdgcn_mfma_f32_16x16x32_bf16(ah, bh, acc[c], 0, 0, 0);
            acc[c] = __builtin_amdgcn_mfma_f32_16x16x32_bf16(ah, bl, acc[c], 0, 0, 0);
            acc[c] = __builtin_amdgcn_mfma_f32_16x16x32_bf16(al, bh, acc[c], 0, 0, 0);
        }
    }
    #pragma unroll
    for (int c = 0; c < 4; ++c)
        #pragma unroll
        for (int r = 0; r < 4; ++r)
            xn[(size_t)(base + q * 4 + r) * HH + c * 16 + r15] = acc[c][r];
}

// ---------------- GEMM 2 fused: h = L2norm(x @ w_self + b + mean) ----------------
__global__ __launch_bounds__(256) void k_gemm_sfin(const float* __restrict__ x,
                                                   const float* __restrict__ w,  // [128][64]
                                                   const float* __restrict__ b_sage,
                                                   const float* __restrict__ msum,
                                                   float* __restrict__ hout) {
    const int l = threadIdx.x & 63;
    const int wv = threadIdx.x >> 6;
    const int base = blockIdx.x * 64 + wv * 16;
    const int r15 = l & 15, q = l >> 4;
    f32x4 acc[4];
    #pragma unroll
    for (int c = 0; c < 4; ++c) acc[c] = (f32x4)0.f;
    #pragma unroll
    for (int s = 0; s < 4; ++s) {
        const float* xr = x + (size_t)(base + r15) * DIN + s * 32 + q * 8;
        float4 a0 = *(const float4*)xr;
        float4 a1 = *(const float4*)(xr + 4);
        float av[8] = {a0.x, a0.y, a0.z, a0.w, a1.x, a1.y, a1.z, a1.w};
        short8v ah, al;
        #pragma unroll
        for (int j = 0; j < 8; ++j) {
            short h = f2bf(av[j]); ah[j] = h; al[j] = f2bf(av[j] - bf2f(h));
        }
        #pragma unroll
        for (int c = 0; c < 4; ++c) {
            const float* wp = w + (size_t)(s * 32 + q * 8) * HH + c * 16 + r15;
            short8v bh, bl;
            #pragma unroll
            for (int j = 0; j < 8; ++j) {
                float v = wp[(size_t)j * HH];
                short h = f2bf(v); bh[j] = h; bl[j] = f2bf(v - bf2f(h));
            }
            acc[c] = __builtin_amdgcn_mfma_f32_16x16x32_bf16(ah, bh, acc[c], 0, 0, 0);
            acc[c] = __builtin_amdgcn_mfma_f32_16x16x32_bf16(ah, bl, acc[c], 0, 0, 0);
            acc[c] = __builtin_amdgcn_mfma_f32_16x16x32_bf16(al, bh, acc[c], 0, 0, 0);
        }
    }
    float val[4][4];
    #pragma unroll
    for (int c = 0; c < 4; ++c) {
        int col = c * 16 + r15;
        float bb = b_sage[col];
        #pragma unroll
        for (int r = 0; r < 4; ++r) {
            int row = base + q * 4 + r;
            val[c][r] = acc[c][r] + bb + msum[(size_t)row * HH + col];
        }
    }
    #pragma unroll
    for (int r = 0; r < 4; ++r) {
        float ss = val[0][r] * val[0][r] + val[1][r] * val[1][r] +
                   val[2][r] * val[2][r] + val[3][r] * val[3][r];
        #pragma unroll
        for (int off = 1; off < 16; off <<= 1) ss += __shfl_xor(ss, off);
        float nrm = sqrtf(ss);
        nrm = nrm > 1e-12f ? nrm : 1e-12f;
        float inv = 1.f / nrm;
        #pragma unroll
        for (int c = 0; c < 4; ++c)
            hout[(size_t)(base + q * 4 + r) * HH + c * 16 + r15] = val[c][r] * inv;
    }
}

// ---------------- degree histogram ----------------
__global__ __launch_bounds__(256) void k_hist(const int* __restrict__ dst,
                                              int* __restrict__ deg_i) {
    int e = blockIdx.x * 256 + threadIdx.x;
    if (e >= NEALL) return;
    int g = e / NEDGE;
    atomicAdd(&deg_i[g * NNODE + dst[e]], 1);
}

// ---------------- per-graph exclusive prefix sum -> cursor ----------------
__global__ __launch_bounds__(256) void k_scan(const int* __restrict__ deg_i,
                                              int* __restrict__ cursor) {
    const int g = blockIdx.x;
    const int t = threadIdx.x;
    const int base = g * NNODE;
    const int start = t * 40;                      // 250*40 = 10000
    const int cnt = start < NNODE ? (NNODE - start < 40 ? NNODE - start : 40) : 0;
    int s = 0;
    for (int i = 0; i < cnt; ++i) s += deg_i[base + start + i];
    __shared__ int sb[256];
    sb[t] = s;
    __syncthreads();
    #pragma unroll
    for (int d = 1; d < 256; d <<= 1) {
        int v = (t >= d) ? sb[t - d] : 0;
        __syncthreads();
        sb[t] += v;
        __syncthreads();
    }
    int run = sb[t] - s;  // exclusive
    for (int i = 0; i < cnt; ++i) {
        int d = deg_i[base + start + i];
        cursor[base + start + i] = run;
        run += d;
    }
}

// ---------------- fill CSR (src ids grouped by dst) ----------------
__global__ __launch_bounds__(256) void k_fill(const int* __restrict__ src,
                                              const int* __restrict__ dst,
                                              int* __restrict__ cursor,
                                              int* __restrict__ csr) {
    int e = blockIdx.x * 256 + threadIdx.x;
    if (e >= NEALL) return;
    int g = e / NEDGE;
    int pos = atomicAdd(&cursor[g * NNODE + dst[e]], 1);
    csr[(size_t)g * NEDGE + pos] = src[e];
}

// ---------------- gather-mean per node ----------------
__global__ __launch_bounds__(256) void k_gath(const int* __restrict__ csr,
                                              const int* __restrict__ cursor,
                                              const int* __restrict__ deg_i,
                                              const float* __restrict__ xn,
                                              float* __restrict__ msum) {
    const int lane = threadIdx.x & 63;
    const int row = blockIdx.x * 4 + (threadIdx.x >> 6);
    if (row >= NROWS) return;
    const int g = row / NNODE;
    const int end = cursor[row];        // post-fill: offset + deg
    const int dg = deg_i[row];
    const int start = end - dg;
    const float* xg = xn + (size_t)g * NNODE * HH;
    const int* cs = csr + (size_t)g * NEDGE;
    float acc = 0.f;
    int j = start;
    for (; j + 4 <= end; j += 4) {
        int s0 = cs[j], s1 = cs[j + 1], s2 = cs[j + 2], s3 = cs[j + 3];
        float v0 = xg[(size_t)s0 * HH + lane];
        float v1 = xg[(size_t)s1 * HH + lane];
        float v2 = xg[(size_t)s2 * HH + lane];
        float v3 = xg[(size_t)s3 * HH + lane];
        acc += v0 + v1 + v2 + v3;
    }
    for (; j < end; ++j) acc += xg[(size_t)cs[j] * HH + lane];
    msum[(size_t)row * HH + lane] = (dg > 0) ? acc / (float)dg : 0.f;
}

__device__ __forceinline__ float sigmoidf_(float v) {
    return 1.0f / (1.0f + __expf(-v));
}

// ---------------- pair / temporal attention ----------------
__global__ __launch_bounds__(256) void k_pair(const float* __restrict__ h,
                                              const int* __restrict__ idx,
                                              const float* __restrict__ w_ff2,
                                              const float* __restrict__ b_ff2p,
                                              const float* __restrict__ w_ff1,
                                              const float* __restrict__ b_ff1p,
                                              const float* __restrict__ w_out,
                                              float* __restrict__ out) {
    const int lane = threadIdx.x & 63;
    const int wave = threadIdx.x >> 6;
    const int p = blockIdx.x * 4 + wave;
    if (p >= NPAIR) return;
    const float wf2_0 = w_ff2[lane], wf2_1 = w_ff2[lane + 64];
    const float wo_0 = w_out[lane], wo_1 = w_out[lane + 64];
    const float bf2 = *b_ff2p, bf1 = *b_ff1p;

    float tv0[TT], tv1[TT], q[TT];
    #pragma unroll
    for (int t = 0; t < TT; ++t) {
        int i0 = idx[t * NPAIR + p];
        int i1 = idx[(TT + t) * NPAIR + p];
        tv0[t] = h[((size_t)t * NNODE + i0) * HH + lane];
        tv1[t] = h[((size_t)(TT + t) * NNODE + i1) * HH + lane];
        float part = tv0[t] * wf2_0 + tv1[t] * wf2_1;
        #pragma unroll
        for (int off = 32; off; off >>= 1) part += __shfl_xor(part, off);
        q[t] = part;
    }

    float s[3];
    #pragma unroll
    for (int k = 1; k <= 3; ++k) {
        float acc = bf1;
        #pragma unroll
        for (int t = 0; t < TT; ++t) {
            float dq = q[t] - (t >= k ? q[t - k] : 0.f);
            float r = dq + bf2;
            r = r > 0.f ? r : 0.f;
            acc += r * w_ff1[t];
        }
        s[k - 1] = acc;
    }
    float m = fmaxf(s[0], fmaxf(s[1], s[2]));
    float e0 = __expf(s[0] - m), e1 = __expf(s[1] - m), e2 = __expf(s[2] - m);
    float inv = 1.f / (e0 + e1 + e2);
    float sw0 = e0 * inv, sw1 = e1 * inv, sw2 = e2 * inv;

    #pragma unroll
    for (int t = 0; t < TT; ++t) {
        float a0, a1;
        {
            float d0 = tv0[t] - (t >= 1 ? tv0[t - 1] : 0.f);
            float d1 = tv1[t] - (t >= 1 ? tv1[t - 1] : 0.f);
            a0 = sw0 * sigmoidf_(d0);
            a1 = sw0 * sigmoidf_(d1);
        }
        {
            float d0 = tv0[t] - (t >= 2 ? tv0[t - 2] : 0.f);
            float d1 = tv1[t] - (t >= 2 ? tv1[t - 2] : 0.f);
            a0 += sw1 * sigmoidf_(d0);
            a1 += sw1 * sigmoidf_(d1);
        }
        {
            float d0 = tv0[t] - (t >= 3 ? tv0[t - 3] : 0.f);
            float d1 = tv1[t] - (t >= 3 ? tv1[t - 3] : 0.f);
            a0 += sw2 * sigmoidf_(d0);
            a1 += sw2 * sigmoidf_(d1);
        }
        float o = tv0[t] * a0 * wo_0 + tv1[t] * a1 * wo_1;
        #pragma unroll
        for (int off = 32; off; off >>= 1) o += __shfl_xor(o, off);
        if (lane == 0) out[t * NPAIR + p] = o;
    }
}

extern "C" void kernel_launch(void* const* d_in, const int* in_sizes, int n_in,
                              void* d_out, int out_size, void* d_ws, size_t ws_size,
                              hipStream_t stream) {
    const float* x      = (const float*)d_in[0];
    const int*   src    = (const int*)d_in[1];
    const int*   dst    = (const int*)d_in[2];
    const int*   idx    = (const int*)d_in[3];
    const float* w_self = (const float*)d_in[4];
    const float* w_neigh= (const float*)d_in[5];
    const float* b_sage = (const float*)d_in[6];
    const float* w_ff2  = (const float*)d_in[7];
    const float* b_ff2  = (const float*)d_in[8];
    const float* w_ff1  = (const float*)d_in[9];
    const float* b_ff1  = (const float*)d_in[10];
    const float* w_out  = (const float*)d_in[11];
    float* out = (float*)d_out;

    char* ws = (char*)d_ws;
    const size_t HB = (size_t)NROWS * HH * sizeof(float);   // 61,440,000
    const size_t NB = (size_t)NROWS * sizeof(int);          //    960,000
    float* xn_h  = (float*)ws;                              // xn, later h (aliased)
    float* msum  = (float*)(ws + HB);
    int*   deg_i = (int*)(ws + 2 * HB);
    int*   cursor= (int*)(ws + 2 * HB + NB);
    int*   csr   = (int*)(ws + 2 * HB + 2 * NB);            // 15,360,000 B

    hipMemsetAsync(deg_i, 0, NB, stream);

    k_gemm_n<<<NROWS / 64, 256, 0, stream>>>(x, w_neigh, xn_h);
    k_hist<<<NEALL / 256, 256, 0, stream>>>(dst, deg_i);
    k_scan<<<NG, 256, 0, stream>>>(deg_i, cursor);
    k_fill<<<NEALL / 256, 256, 0, stream>>>(src, dst, cursor, csr);
    k_gath<<<NROWS / 4, 256, 0, stream>>>(csr, cursor, deg_i, xn_h, msum);
    k_gemm_sfin<<<NROWS / 64, 256, 0, stream>>>(x, w_self, b_sage, msum, xn_h);
    k_pair<<<NPAIR / 4, 256, 0, stream>>>(xn_h, idx, w_ff2, b_ff2, w_ff1, b_ff1,
                                          w_out, out);
}